// Round 2
// baseline (884.204 us; speedup 1.0000x reference)
//
#include <hip/hip_runtime.h>

typedef __attribute__((ext_vector_type(8))) short bf16x8;
typedef __attribute__((ext_vector_type(4))) float f32x4;
typedef __attribute__((ext_vector_type(4))) int i32x4;
typedef __attribute__((ext_vector_type(4))) unsigned short u16x4;

#define KDIM 256
#define HWSZ 4096
#define NOUT 765
#define NOUTP 768

// Anchors in PIXEL units: w_a = ANCHORS/16 (grid units) and every use multiplies
// by STRIDE=16, so pixel units are exact. Index 9 = dummy for padded o (never stored).
__constant__ float c_AW[10] = {10.f,16.f,33.f,30.f,62.f,59.f,116.f,156.f,373.f,0.f};
__constant__ float c_AH[10] = {13.f,30.f,23.f,61.f,45.f,119.f,90.f,198.f,326.f,0.f};

__device__ __forceinline__ unsigned short f2bf(float f) {
  unsigned u = __builtin_bit_cast(unsigned, f);
  u += 0x7fffu + ((u >> 16) & 1u);   // RNE
  return (unsigned short)(u >> 16);
}

__device__ __forceinline__ float sigf(float t) {
  return 1.0f / (1.0f + __expf(-t));
}

// ---- kernel 1: conv_w (765x256 f32) -> padded bf16 (768x256), rows 765..767 = 0
__global__ void prep_w(const float* __restrict__ cw, unsigned short* __restrict__ wbf) {
  int e = (blockIdx.x * 256 + threadIdx.x) * 4;
  int o = e >> 8, col = e & 255;
  f32x4 v = {0.f, 0.f, 0.f, 0.f};
  if (o < NOUT) v = *reinterpret_cast<const f32x4*>(cw + o * KDIM + col);
  u16x4 u = { f2bf(v.x), f2bf(v.y), f2bf(v.z), f2bf(v.w) };
  *reinterpret_cast<u16x4*>(wbf + e) = u;
}

// ---- kernel 2: block = (batch, image row, row half) -> 32 pixels x all 765 outputs.
// 8 waves; wave wv owns channels [96wv, 96wv+96) x 32 px. acc = 6x2 f32x4 = 48 VGPR.
// Epilogue stages decoded output into LDS (3 anchors at a time) and streams dense,
// 16B-aligned dwordx4 writes to the contiguous per-anchor slabs.
__global__ __launch_bounds__(512, 8) void yolo_main(
    const float* __restrict__ xin,
    const unsigned short* __restrict__ wbf,
    const float* __restrict__ bias,
    float* __restrict__ out)
{
  __shared__ __align__(16) char smem[3 * 2720 * 4];          // 32640 B
  unsigned short* xT   = reinterpret_cast<unsigned short*>(smem); // [32][256] bf16, swizzled (16 KB)
  float*          stg  = reinterpret_cast<float*>(smem);          // [3][32*85] f32 (32.6 KB)

  const int bid  = blockIdx.x;
  const int ph   = bid & 1;           // row half: pixels [32ph, 32ph+32)
  const int pc   = (bid >> 1) & 63;   // image row y
  const int b    = bid >> 7;          // batch
  const int tid  = threadIdx.x;
  const int lane = tid & 63;
  const int wv   = tid >> 6;

  // ---------- stage X^T into LDS (f32 -> bf16, k-bits 3..5 XOR-swizzled by px&7) ----------
  {
    const int px     = tid & 31;
    const int c0base = (tid >> 5) << 3;          // 0..120 step 8
    const float* xsrc = xin + (size_t)b * KDIM * HWSZ + pc * 64 + ph * 32 + px;
    const int sw = (px & 7) << 3;
    #pragma unroll
    for (int i = 0; i < 2; ++i) {
      const int c0 = c0base + 128 * i;
      float v[8];
      #pragma unroll
      for (int j = 0; j < 8; ++j) v[j] = xsrc[(size_t)(c0 + j) * HWSZ];
      union { i32x4 q; unsigned short us[8]; } pk;
      #pragma unroll
      for (int j = 0; j < 8; ++j) pk.us[j] = f2bf(v[j]);
      *reinterpret_cast<i32x4*>(&xT[(px << 8) + (c0 ^ sw)]) = pk.q;
    }
  }
  __syncthreads();

  const int g     = lane >> 4;
  const int r16   = lane & 15;
  const int obase = wv * 96;

  f32x4 acc[6][2];
  #pragma unroll
  for (int ot = 0; ot < 6; ++ot) {
    acc[ot][0] = f32x4{0.f, 0.f, 0.f, 0.f};
    acc[ot][1] = f32x4{0.f, 0.f, 0.f, 0.f};
  }

  const unsigned short* wptr = wbf + (unsigned)(obase + r16) * KDIM + 8 * g;
  const int xb0 = (r16 << 8);          // px = r16       (pt = 0)
  const int xb1 = ((16 + r16) << 8);   // px = 16 + r16  (pt = 1)
  const int sw0 = (r16 & 7) << 3;      // (16+r16)&7 == r16&7, same swizzle

  #pragma unroll
  for (int kk = 0; kk < 8; ++kk) {
    const int ke = (kk * 32 + 8 * g) ^ sw0;
    bf16x8 x0 = __builtin_bit_cast(bf16x8, *reinterpret_cast<const i32x4*>(&xT[xb0 + ke]));
    bf16x8 x1 = __builtin_bit_cast(bf16x8, *reinterpret_cast<const i32x4*>(&xT[xb1 + ke]));
    #pragma unroll
    for (int ot = 0; ot < 6; ++ot) {
      bf16x8 w = __builtin_bit_cast(bf16x8,
          *reinterpret_cast<const i32x4*>(wptr + ot * 16 * KDIM + kk * 32));
      acc[ot][0] = __builtin_amdgcn_mfma_f32_16x16x32_bf16(x0, w, acc[ot][0], 0, 0, 0);
      acc[ot][1] = __builtin_amdgcn_mfma_f32_16x16x32_bf16(x1, w, acc[ot][1], 0, 0, 0);
    }
  }

  __syncthreads();   // all xT reads complete before stg overwrites smem

  // preload bias (o >= 765 lanes read dummy, never deposited)
  float bi[6];
  #pragma unroll
  for (int ot = 0; ot < 6; ++ot) {
    const int o = obase + ot * 16 + r16;
    bi[ot] = bias[o < NOUT ? o : 0];
  }
  const float ys  = (float)pc * 16.0f;
  const float xs0 = (float)(ph * 32) * 16.0f;

  // ---------- 3 iterations x 3 anchors: deposit decoded values, then dense copy-out ----------
  #pragma unroll 1
  for (int t3 = 0; t3 < 3; ++t3) {
    const int alo = 3 * t3;
    // deposit: D layout col=r16 -> o, row=4g+r -> px = pt*16+4g+r
    #pragma unroll
    for (int ot = 0; ot < 6; ++ot) {
      const int o = obase + ot * 16 + r16;
      const int a = o / 85;                       // 9 for padded o -> never matches
      if (a >= alo && a < alo + 3) {
        const int ch = o - a * 85;
        const float aw = c_AW[a], ah = c_AH[a];
        float* sdst = stg + (a - alo) * 2720 + ch;
        #pragma unroll
        for (int pt = 0; pt < 2; ++pt) {
          #pragma unroll
          for (int r = 0; r < 4; ++r) {
            const int   pxl = pt * 16 + g * 4 + r;
            const float tv  = acc[ot][pt][r] + bi[ot];
            float val;
            if (ch >= 4)      val = sigf(tv);
            else if (ch == 0) val = (sigf(tv) - 0.5f) * aw + xs0 + (float)pxl * 16.0f;
            else if (ch == 1) val = (sigf(tv) - 0.5f) * ah + ys;
            else if (ch == 2) val = __expf(tv) * aw;
            else              val = __expf(tv) * ah;
            sdst[pxl * 85] = val;
          }
        }
      }
    }
    __syncthreads();
    // copy: 3 anchors x 680 dwordx4 quads, fully dense + 16B-aligned
    #pragma unroll 1
    for (int q = tid; q < 2040; q += 512) {
      const int al = (q >= 1360) ? 2 : (q >= 680 ? 1 : 0);
      const int a  = alo + al;
      const f32x4 v = *reinterpret_cast<const f32x4*>(stg + q * 4);
      const unsigned dstdw = ((unsigned)(b * 9 + a) * HWSZ + (unsigned)(pc * 64 + ph * 32)) * 85u
                           + (unsigned)(q - al * 680) * 4u;
      *reinterpret_cast<f32x4*>(out + dstdw) = v;
    }
    __syncthreads();
  }
}

extern "C" void kernel_launch(void* const* d_in, const int* in_sizes, int n_in,
                              void* d_out, int out_size, void* d_ws, size_t ws_size,
                              hipStream_t stream) {
  const float* xin = (const float*)d_in[0];
  const float* cw  = (const float*)d_in[1];
  const float* cb  = (const float*)d_in[2];
  float* out = (float*)d_out;
  unsigned short* wbf = (unsigned short*)d_ws;   // 768*256*2 = 393216 bytes

  prep_w<<<dim3((NOUTP * KDIM / 4) / 256), dim3(256), 0, stream>>>(cw, wbf);
  yolo_main<<<dim3(16 * 64 * 2), dim3(512), 0, stream>>>(xin, wbf, cb, out);
}

// Round 3
// 254.453 us; speedup vs baseline: 3.4749x; 3.4749x over previous
//
#include <hip/hip_runtime.h>

typedef __attribute__((ext_vector_type(8))) short bf16x8;
typedef __attribute__((ext_vector_type(4))) float f32x4;
typedef __attribute__((ext_vector_type(4))) int i32x4;
typedef __attribute__((ext_vector_type(4))) unsigned short u16x4;

#define KDIM 256
#define HWSZ 4096
#define NOUT 765
#define NOUTP 768

// Anchors in PIXEL units: w_a = ANCHORS/16 (grid units) and every use multiplies
// by STRIDE=16, so pixel units are exact. Index 9 = dummy for padded o (never stored).
__constant__ float c_AW[10] = {10.f,16.f,33.f,30.f,62.f,59.f,116.f,156.f,373.f,0.f};
__constant__ float c_AH[10] = {13.f,30.f,23.f,61.f,45.f,119.f,90.f,198.f,326.f,0.f};

__device__ __forceinline__ unsigned short f2bf(float f) {
  unsigned u = __builtin_bit_cast(unsigned, f);
  u += 0x7fffu + ((u >> 16) & 1u);   // RNE
  return (unsigned short)(u >> 16);
}

__device__ __forceinline__ float sigf(float t) {
  return 1.0f / (1.0f + __expf(-t));
}

// ---- kernel 1: conv_w (765x256 f32) -> padded bf16 (768x256), rows 765..767 = 0
__global__ void prep_w(const float* __restrict__ cw, unsigned short* __restrict__ wbf) {
  int e = (blockIdx.x * 256 + threadIdx.x) * 4;
  int o = e >> 8, col = e & 255;
  f32x4 v = {0.f, 0.f, 0.f, 0.f};
  if (o < NOUT) v = *reinterpret_cast<const f32x4*>(cw + o * KDIM + col);
  u16x4 u = { f2bf(v.x), f2bf(v.y), f2bf(v.z), f2bf(v.w) };
  *reinterpret_cast<u16x4*>(wbf + e) = u;
}

// ---- kernel 2: block = (batch, image row, row half) -> 32 pixels x all 765 outputs.
// 8 waves; wave wv owns channels [96wv, 96wv+96) x 32 px. acc = 6x2 f32x4 = 48 VGPR.
// __launch_bounds__(512,4): 128-VGPR budget -> no spill (round 2's (512,8) forced
// 32 VGPRs and spilled everything: 3 GB of scratch HBM traffic).
// Epilogue stages decoded output into LDS (3 anchors at a time) and streams dense,
// 16B-aligned dwordx4 writes to the contiguous per-anchor slabs.
__global__ __launch_bounds__(512, 4) void yolo_main(
    const float* __restrict__ xin,
    const unsigned short* __restrict__ wbf,
    const float* __restrict__ bias,
    float* __restrict__ out)
{
  __shared__ __align__(16) char smem[3 * 2720 * 4];          // 32640 B
  unsigned short* xT   = reinterpret_cast<unsigned short*>(smem); // [32][256] bf16, swizzled (16 KB)
  float*          stg  = reinterpret_cast<float*>(smem);          // [3][32*85] f32 (32.6 KB)

  const int bid  = blockIdx.x;
  const int ph   = bid & 1;           // row half: pixels [32ph, 32ph+32)
  const int pc   = (bid >> 1) & 63;   // image row y
  const int b    = bid >> 7;          // batch
  const int tid  = threadIdx.x;
  const int lane = tid & 63;
  const int wv   = tid >> 6;

  // ---------- stage X^T into LDS (f32 -> bf16, k-bits 3..5 XOR-swizzled by px&7) ----------
  {
    const int px     = tid & 31;
    const int c0base = (tid >> 5) << 3;          // 0..120 step 8
    const float* xsrc = xin + (size_t)b * KDIM * HWSZ + pc * 64 + ph * 32 + px;
    const int sw = (px & 7) << 3;
    #pragma unroll
    for (int i = 0; i < 2; ++i) {
      const int c0 = c0base + 128 * i;
      float v[8];
      #pragma unroll
      for (int j = 0; j < 8; ++j) v[j] = xsrc[(size_t)(c0 + j) * HWSZ];
      union { i32x4 q; unsigned short us[8]; } pk;
      #pragma unroll
      for (int j = 0; j < 8; ++j) pk.us[j] = f2bf(v[j]);
      *reinterpret_cast<i32x4*>(&xT[(px << 8) + (c0 ^ sw)]) = pk.q;
    }
  }
  __syncthreads();

  const int g     = lane >> 4;
  const int r16   = lane & 15;
  const int obase = wv * 96;

  f32x4 acc[6][2];
  #pragma unroll
  for (int ot = 0; ot < 6; ++ot) {
    acc[ot][0] = f32x4{0.f, 0.f, 0.f, 0.f};
    acc[ot][1] = f32x4{0.f, 0.f, 0.f, 0.f};
  }

  const unsigned short* wptr = wbf + (unsigned)(obase + r16) * KDIM + 8 * g;
  const int xb0 = (r16 << 8);          // px = r16       (pt = 0)
  const int xb1 = ((16 + r16) << 8);   // px = 16 + r16  (pt = 1)
  const int sw0 = (r16 & 7) << 3;      // (16+r16)&7 == r16&7, same swizzle

  #pragma unroll
  for (int kk = 0; kk < 8; ++kk) {
    const int ke = (kk * 32 + 8 * g) ^ sw0;
    bf16x8 x0 = __builtin_bit_cast(bf16x8, *reinterpret_cast<const i32x4*>(&xT[xb0 + ke]));
    bf16x8 x1 = __builtin_bit_cast(bf16x8, *reinterpret_cast<const i32x4*>(&xT[xb1 + ke]));
    #pragma unroll
    for (int ot = 0; ot < 6; ++ot) {
      bf16x8 w = __builtin_bit_cast(bf16x8,
          *reinterpret_cast<const i32x4*>(wptr + ot * 16 * KDIM + kk * 32));
      acc[ot][0] = __builtin_amdgcn_mfma_f32_16x16x32_bf16(x0, w, acc[ot][0], 0, 0, 0);
      acc[ot][1] = __builtin_amdgcn_mfma_f32_16x16x32_bf16(x1, w, acc[ot][1], 0, 0, 0);
    }
  }

  __syncthreads();   // all xT reads complete before stg overwrites smem

  // preload bias (o >= 765 lanes read dummy, never deposited)
  float bi[6];
  #pragma unroll
  for (int ot = 0; ot < 6; ++ot) {
    const int o = obase + ot * 16 + r16;
    bi[ot] = bias[o < NOUT ? o : 0];
  }
  const float ys  = (float)pc * 16.0f;
  const float xs0 = (float)(ph * 32) * 16.0f;

  // ---------- 3 iterations x 3 anchors: deposit decoded values, then dense copy-out ----------
  #pragma unroll 1
  for (int t3 = 0; t3 < 3; ++t3) {
    const int alo = 3 * t3;
    // deposit: D layout col=r16 -> o, row=4g+r -> px = pt*16+4g+r
    #pragma unroll
    for (int ot = 0; ot < 6; ++ot) {
      const int o = obase + ot * 16 + r16;
      const int a = o / 85;                       // 9 for padded o -> never matches
      if (a >= alo && a < alo + 3) {
        const int ch = o - a * 85;
        const float aw = c_AW[a], ah = c_AH[a];
        float* sdst = stg + (a - alo) * 2720 + ch;
        #pragma unroll
        for (int pt = 0; pt < 2; ++pt) {
          #pragma unroll
          for (int r = 0; r < 4; ++r) {
            const int   pxl = pt * 16 + g * 4 + r;
            const float tv  = acc[ot][pt][r] + bi[ot];
            float val;
            if (ch >= 4)      val = sigf(tv);
            else if (ch == 0) val = (sigf(tv) - 0.5f) * aw + xs0 + (float)pxl * 16.0f;
            else if (ch == 1) val = (sigf(tv) - 0.5f) * ah + ys;
            else if (ch == 2) val = __expf(tv) * aw;
            else              val = __expf(tv) * ah;
            sdst[pxl * 85] = val;
          }
        }
      }
    }
    __syncthreads();
    // copy: 3 anchors x 680 dwordx4 quads, fully dense + 16B-aligned
    #pragma unroll 1
    for (int q = tid; q < 2040; q += 512) {
      const int al = (q >= 1360) ? 2 : (q >= 680 ? 1 : 0);
      const int a  = alo + al;
      const f32x4 v = *reinterpret_cast<const f32x4*>(stg + q * 4);
      const unsigned dstdw = ((unsigned)(b * 9 + a) * HWSZ + (unsigned)(pc * 64 + ph * 32)) * 85u
                           + (unsigned)(q - al * 680) * 4u;
      *reinterpret_cast<f32x4*>(out + dstdw) = v;
    }
    __syncthreads();
  }
}

extern "C" void kernel_launch(void* const* d_in, const int* in_sizes, int n_in,
                              void* d_out, int out_size, void* d_ws, size_t ws_size,
                              hipStream_t stream) {
  const float* xin = (const float*)d_in[0];
  const float* cw  = (const float*)d_in[1];
  const float* cb  = (const float*)d_in[2];
  float* out = (float*)d_out;
  unsigned short* wbf = (unsigned short*)d_ws;   // 768*256*2 = 393216 bytes

  prep_w<<<dim3((NOUTP * KDIM / 4) / 256), dim3(256), 0, stream>>>(cw, wbf);
  yolo_main<<<dim3(16 * 64 * 2), dim3(512), 0, stream>>>(xin, wbf, cb, out);
}

// Round 4
// 211.514 us; speedup vs baseline: 4.1804x; 1.2030x over previous
//
#include <hip/hip_runtime.h>

typedef __attribute__((ext_vector_type(8))) short bf16x8;
typedef __attribute__((ext_vector_type(4))) float f32x4;
typedef __attribute__((ext_vector_type(4))) int i32x4;
typedef __attribute__((ext_vector_type(4))) unsigned short u16x4;

#define KDIM 256
#define HWSZ 4096
#define NOUT 765
#define NOUTP 768

// Anchors in PIXEL units: w_a = ANCHORS/16 (grid units) and every use multiplies
// by STRIDE=16, so pixel units are exact. Index 9 = dummy for padded o (never stored).
__constant__ float c_AW[10] = {10.f,16.f,33.f,30.f,62.f,59.f,116.f,156.f,373.f,0.f};
__constant__ float c_AH[10] = {13.f,30.f,23.f,61.f,45.f,119.f,90.f,198.f,326.f,0.f};

__device__ __forceinline__ unsigned short f2bf(float f) {
  unsigned u = __builtin_bit_cast(unsigned, f);
  u += 0x7fffu + ((u >> 16) & 1u);   // RNE
  return (unsigned short)(u >> 16);
}

__device__ __forceinline__ float sigf(float t) {
  return 1.0f / (1.0f + __expf(-t));
}

// ---- kernel 1: conv_w (765x256 f32) -> padded bf16 (768x256), rows 765..767 = 0
__global__ void prep_w(const float* __restrict__ cw, unsigned short* __restrict__ wbf) {
  int e = (blockIdx.x * 256 + threadIdx.x) * 4;
  int o = e >> 8, col = e & 255;
  f32x4 v = {0.f, 0.f, 0.f, 0.f};
  if (o < NOUT) v = *reinterpret_cast<const f32x4*>(cw + o * KDIM + col);
  u16x4 u = { f2bf(v.x), f2bf(v.y), f2bf(v.z), f2bf(v.w) };
  *reinterpret_cast<u16x4*>(wbf + e) = u;
}

// ---- kernel 2: block = (batch, image row, row half) -> 32 pixels x all 765 outputs.
// 8 waves; wave wv owns channels [96wv, 96wv+96) x 32 px. acc = 6x2 f32x4 = 48 AGPR.
// NO min-waves launch bound: on this toolchain (512,4) forced 64 VGPR and (512,8)
// forced 32 VGPR -> massive scratch spill (rounds 2-3: +0.3..2.6 GB HBM traffic).
// Unconstrained the kernel fits ~96-110 VGPR with zero spill (round 1 evidence).
// Epilogue stages decoded output into LDS (3 anchors at a time) and streams dense,
// 16B-aligned dwordx4 writes to the contiguous 10880B per-anchor slabs.
__global__ __launch_bounds__(512) void yolo_main(
    const float* __restrict__ xin,
    const unsigned short* __restrict__ wbf,
    const float* __restrict__ bias,
    float* __restrict__ out)
{
  __shared__ __align__(16) char smem[3 * 2720 * 4];          // 32640 B
  unsigned short* xT   = reinterpret_cast<unsigned short*>(smem); // [32][256] bf16, swizzled (16 KB)
  float*          stg  = reinterpret_cast<float*>(smem);          // [3][32*85] f32 (32.6 KB)

  const int bid  = blockIdx.x;
  const int ph   = bid & 1;           // row half: pixels [32ph, 32ph+32)
  const int pc   = (bid >> 1) & 63;   // image row y
  const int b    = bid >> 7;          // batch
  const int tid  = threadIdx.x;
  const int lane = tid & 63;
  const int wv   = tid >> 6;

  // ---------- stage X^T into LDS (f32 -> bf16, k-bits 3..5 XOR-swizzled by px&7) ----------
  {
    const int px     = tid & 31;
    const int c0base = (tid >> 5) << 3;          // 0..120 step 8
    const float* xsrc = xin + (size_t)b * KDIM * HWSZ + pc * 64 + ph * 32 + px;
    const int sw = (px & 7) << 3;
    #pragma unroll
    for (int i = 0; i < 2; ++i) {
      const int c0 = c0base + 128 * i;
      float v[8];
      #pragma unroll
      for (int j = 0; j < 8; ++j) v[j] = xsrc[(size_t)(c0 + j) * HWSZ];
      union { i32x4 q; unsigned short us[8]; } pk;
      #pragma unroll
      for (int j = 0; j < 8; ++j) pk.us[j] = f2bf(v[j]);
      *reinterpret_cast<i32x4*>(&xT[(px << 8) + (c0 ^ sw)]) = pk.q;
    }
  }
  __syncthreads();

  const int g     = lane >> 4;
  const int r16   = lane & 15;
  const int obase = wv * 96;

  f32x4 acc[6][2];
  #pragma unroll
  for (int ot = 0; ot < 6; ++ot) {
    acc[ot][0] = f32x4{0.f, 0.f, 0.f, 0.f};
    acc[ot][1] = f32x4{0.f, 0.f, 0.f, 0.f};
  }

  const unsigned short* wptr = wbf + (unsigned)(obase + r16) * KDIM + 8 * g;
  const int xb0 = (r16 << 8);          // px = r16       (pt = 0)
  const int xb1 = ((16 + r16) << 8);   // px = 16 + r16  (pt = 1)
  const int sw0 = (r16 & 7) << 3;      // (16+r16)&7 == r16&7, same swizzle

  #pragma unroll
  for (int kk = 0; kk < 8; ++kk) {
    const int ke = (kk * 32 + 8 * g) ^ sw0;
    bf16x8 x0 = __builtin_bit_cast(bf16x8, *reinterpret_cast<const i32x4*>(&xT[xb0 + ke]));
    bf16x8 x1 = __builtin_bit_cast(bf16x8, *reinterpret_cast<const i32x4*>(&xT[xb1 + ke]));
    #pragma unroll
    for (int ot = 0; ot < 6; ++ot) {
      bf16x8 w = __builtin_bit_cast(bf16x8,
          *reinterpret_cast<const i32x4*>(wptr + ot * 16 * KDIM + kk * 32));
      acc[ot][0] = __builtin_amdgcn_mfma_f32_16x16x32_bf16(x0, w, acc[ot][0], 0, 0, 0);
      acc[ot][1] = __builtin_amdgcn_mfma_f32_16x16x32_bf16(x1, w, acc[ot][1], 0, 0, 0);
    }
  }

  __syncthreads();   // all xT reads complete before stg overwrites smem

  // preload bias (o >= 765 lanes read dummy, never deposited)
  float bi[6];
  #pragma unroll
  for (int ot = 0; ot < 6; ++ot) {
    const int o = obase + ot * 16 + r16;
    bi[ot] = bias[o < NOUT ? o : 0];
  }
  const float ys  = (float)pc * 16.0f;
  const float xs0 = (float)(ph * 32) * 16.0f;

  // ---------- 3 iterations x 3 anchors: deposit decoded values, then dense copy-out ----------
  #pragma unroll 1
  for (int t3 = 0; t3 < 3; ++t3) {
    const int alo = 3 * t3;
    // deposit: D layout col=r16 -> o, row=4g+r -> px = pt*16+4g+r
    #pragma unroll
    for (int ot = 0; ot < 6; ++ot) {
      const int o = obase + ot * 16 + r16;
      const int a = o / 85;                       // 9 for padded o -> never matches
      if (a >= alo && a < alo + 3) {
        const int ch = o - a * 85;
        const float aw = c_AW[a], ah = c_AH[a];
        float* sdst = stg + (a - alo) * 2720 + ch;
        #pragma unroll
        for (int pt = 0; pt < 2; ++pt) {
          #pragma unroll
          for (int r = 0; r < 4; ++r) {
            const int   pxl = pt * 16 + g * 4 + r;
            const float tv  = acc[ot][pt][r] + bi[ot];
            float val;
            if (ch >= 4)      val = sigf(tv);
            else if (ch == 0) val = (sigf(tv) - 0.5f) * aw + xs0 + (float)pxl * 16.0f;
            else if (ch == 1) val = (sigf(tv) - 0.5f) * ah + ys;
            else if (ch == 2) val = __expf(tv) * aw;
            else              val = __expf(tv) * ah;
            sdst[pxl * 85] = val;
          }
        }
      }
    }
    __syncthreads();
    // copy: 3 anchors x 680 dwordx4 quads, fully dense + 16B-aligned (slab = 10880B, 64B-aligned)
    #pragma unroll 1
    for (int q = tid; q < 2040; q += 512) {
      const int al = (q >= 1360) ? 2 : (q >= 680 ? 1 : 0);
      const int a  = alo + al;
      const f32x4 v = *reinterpret_cast<const f32x4*>(stg + q * 4);
      const unsigned dstdw = ((unsigned)(b * 9 + a) * HWSZ + (unsigned)(pc * 64 + ph * 32)) * 85u
                           + (unsigned)(q - al * 680) * 4u;
      *reinterpret_cast<f32x4*>(out + dstdw) = v;
    }
    __syncthreads();
  }
}

extern "C" void kernel_launch(void* const* d_in, const int* in_sizes, int n_in,
                              void* d_out, int out_size, void* d_ws, size_t ws_size,
                              hipStream_t stream) {
  const float* xin = (const float*)d_in[0];
  const float* cw  = (const float*)d_in[1];
  const float* cb  = (const float*)d_in[2];
  float* out = (float*)d_out;
  unsigned short* wbf = (unsigned short*)d_ws;   // 768*256*2 = 393216 bytes

  prep_w<<<dim3((NOUTP * KDIM / 4) / 256), dim3(256), 0, stream>>>(cw, wbf);
  yolo_main<<<dim3(16 * 64 * 2), dim3(512), 0, stream>>>(xin, wbf, cb, out);
}